// Round 15
// baseline (150.214 us; speedup 1.0000x reference)
//
#include <hip/hip_runtime.h>
#include <hip/hip_bf16.h>

// Round 14 = r9 exact structure + 2-tile-per-barrier unroll.
// Eliminated with counters: bank conflicts (r9: 14.7M->0), occupancy
// (r10/r12: 2x waves -> busy-times constant, dur worse), LDS issue pressure
// (r13: reads halved -> flat). Invariant: MFMA-busy ~20us, VALU-busy ~34us,
// dur ~72-79us => ~38us where neither pipe issues. Surviving suspect: the
// 32 barrier intervals, each with a full vmcnt/lgkmcnt drain + 8-wave
// lockstep. r14 halves them: stage TWO 64-key tiles per sync (LDS 40->72KB,
// still 2 blocks/CU), prefetch 2 tiles ahead (2x latency window), compute
// 2 independent QK->SM->PV chains per barrier interval (2x schedulable ILP).
// Work decomposition (16q x 64k per wave), conflict-free layouts, staging
// maps, fixed-base softmax, epilogue: verbatim r9. One variable changed.

typedef __attribute__((ext_vector_type(8))) short bf16x8;
typedef __attribute__((ext_vector_type(4))) short bf16x4;
typedef __attribute__((ext_vector_type(4))) float f32x4;

#define B_ 2
#define S_ 2048
#define H_ 16
#define D_ 64
#define BQ 128
#define BK 64
#define NT (S_ / BK)
#define NP (NT / 2)            // 16 tile-pairs = 16 barrier intervals
#define ROWSZ (H_ * D_)        // 1024 floats between s rows

#define LOG2E  1.44269504088896340736f
#define SCALE2 (0.125f * LOG2E)

__device__ __forceinline__ unsigned pack2(float a, float b) {
    union { __hip_bfloat162 h; unsigned u; } x;
    x.h = __float22bfloat162_rn(make_float2(a, b));   // v_cvt_pk_bf16_f32
    return x.u;
}

__device__ __forceinline__ float fexp2(float x) {
#if __has_builtin(__builtin_amdgcn_exp2f)
    return __builtin_amdgcn_exp2f(x);
#else
    return __expf(x * 0.69314718055994531f);
#endif
}

__device__ __forceinline__ f32x4 mfma16(bf16x4 a, bf16x4 b, f32x4 c) {
#if __has_builtin(__builtin_amdgcn_mfma_f32_16x16x16bf16_1k)
    return __builtin_amdgcn_mfma_f32_16x16x16bf16_1k(a, b, c, 0, 0, 0);
#else
    bf16x8 a8 = {a[0], a[1], a[2], a[3], 0, 0, 0, 0};
    bf16x8 b8 = {b[0], b[1], b[2], b[3], 0, 0, 0, 0};
    return __builtin_amdgcn_mfma_f32_16x16x32_bf16(a8, b8, c, 0, 0, 0);
#endif
}

__global__ __launch_bounds__(512, 4)
void fattn_kernel(const float* __restrict__ qg,
                  const float* __restrict__ kg,
                  const float* __restrict__ vg,
                  const float* __restrict__ maskg,
                  float* __restrict__ outg)
{
    // 2 double-buffers x 2 tile-slots: 72KB total -> 2 blocks/CU (144/160KB)
    __shared__ __attribute__((aligned(16))) ushort Ks[2][8192];
    __shared__ __attribute__((aligned(16))) ushort Vt[2][8192];
    __shared__ __attribute__((aligned(16))) float  Em[S_];   // mask * log2e

    const int qt = blockIdx.x, h = blockIdx.y, b = blockIdx.z;
    const int tid = threadIdx.x;
    const int w = tid >> 6, lane = tid & 63, g = lane >> 4, l15 = lane & 15;

    // ---- stage pre-scaled mask to LDS (once) ----
    {
        float4 mv = *(const float4*)(maskg + (size_t)b * S_ + tid * 4);
        *(float4*)&Em[tid * 4] = make_float4(mv.x * LOG2E, mv.y * LOG2E,
                                             mv.z * LOG2E, mv.w * LOG2E);
    }

    // ---- Q fragment (B-operand, x32), scale folded in ----
    const int qrow = qt * BQ + w * 16 + l15;
    const float* qp = qg + (size_t)(b * S_ + qrow) * ROWSZ + h * D_;
    bf16x8 qf[2];
#pragma unroll
    for (int half = 0; half < 2; ++half) {
        float4 f0 = *(const float4*)(qp + half * 32 + g * 8);
        float4 f1 = *(const float4*)(qp + half * 32 + g * 8 + 4);
        union { bf16x8 v; uint4 u; } x;
        x.u = make_uint4(pack2(f0.x * SCALE2, f0.y * SCALE2),
                         pack2(f0.z * SCALE2, f0.w * SCALE2),
                         pack2(f1.x * SCALE2, f1.y * SCALE2),
                         pack2(f1.z * SCALE2, f1.w * SCALE2));
        qf[half] = x.v;
    }

    // ---- staging maps (verbatim r9; per tile-slot) ----
    const int skey = tid >> 4;
    const int sd   = (tid & 15) * 4;
    const int kw0 = (skey >> 4) * 1024
                  + ((sd >> 3) + ((skey >> 3) & 1) * 8) * 64
                  + (((skey & 7) ^ (sd >> 3)) << 3) + (sd & 7);
    const int kw1 = kw0 + 2048;
    const int vwA = ((w >> 1) * 4 + (lane >> 4)) * 256
                  + ((2 * w) & 3) * 64 + (lane & 15) * 4;
    const int vwB = vwA + 64;

    const size_t kvbase = (size_t)b * S_ * ROWSZ + h * D_;

    float4 kpre[2][2];
    float  vpre[2][8];
    auto prefetch = [&](int ip) {
#pragma unroll
        for (int s = 0; s < 2; ++s) {
            const float* kb = kg + kvbase + (size_t)(2 * ip + s) * BK * ROWSZ;
            kpre[s][0] = *(const float4*)(kb + (size_t)skey * ROWSZ + sd);
            kpre[s][1] = *(const float4*)(kb + (size_t)(skey + 32) * ROWSZ + sd);
            const float* vb = vg + kvbase + (size_t)(2 * ip + s) * BK * ROWSZ + lane;
#pragma unroll
            for (int i = 0; i < 8; ++i)
                vpre[s][i] = vb[(size_t)(w * 8 + i) * ROWSZ];
        }
    };
    auto stage = [&](int buf) {
#pragma unroll
        for (int s = 0; s < 2; ++s) {
            *(uint2*)&Ks[buf][s * 4096 + kw0] =
                make_uint2(pack2(kpre[s][0].x, kpre[s][0].y),
                           pack2(kpre[s][0].z, kpre[s][0].w));
            *(uint2*)&Ks[buf][s * 4096 + kw1] =
                make_uint2(pack2(kpre[s][1].x, kpre[s][1].y),
                           pack2(kpre[s][1].z, kpre[s][1].w));
            *(uint2*)&Vt[buf][s * 4096 + vwA] =
                make_uint2(pack2(vpre[s][0], vpre[s][1]),
                           pack2(vpre[s][2], vpre[s][3]));
            *(uint2*)&Vt[buf][s * 4096 + vwB] =
                make_uint2(pack2(vpre[s][4], vpre[s][5]),
                           pack2(vpre[s][6], vpre[s][7]));
        }
    };

    float l_r = 0.0f;                   // per-lane (q=l15) partial denominator
    f32x4 o_acc[4];
#pragma unroll
    for (int t = 0; t < 4; ++t) o_acc[t] = (f32x4){0.f, 0.f, 0.f, 0.f};

    prefetch(0);
    stage(0);
    __syncthreads();                    // also covers Em staging

    // ---- read bases (thread-constant; reads at immediate offsets) ----
    const int krd0 = (g + (l15 >> 3) * 8) * 64 + (((l15 & 7) ^ g) << 3);
    const int krd1 = (g + 4 + (l15 >> 3) * 8) * 64 + (((l15 & 7) ^ (g + 4)) << 3);
    const int vrd = g * 64 + l15 * 4;

    for (int ip = 0; ip < NP; ++ip) {
        const int cur = ip & 1;
        if (ip + 1 < NP) prefetch(ip + 1);   // 20 loads in flight, 2-tile window

        const ushort* ks = Ks[cur];
        const ushort* vt = Vt[cur];
        bf16x4 pf[2][4];                     // P fragments for both tiles

        // ---- QK + fused softmax, tiles s=0,1 (independent chains) ----
#pragma unroll
        for (int s = 0; s < 2; ++s) {
            float rs = 0.f;
#pragma unroll
            for (int t = 0; t < 4; ++t) {
                f32x4 acc = *(const f32x4*)&Em[(2 * ip + s) * BK + t * 16 + g * 4];
                bf16x8 kf0 = *(const bf16x8*)&ks[s * 4096 + t * 1024 + krd0];
                bf16x8 kf1 = *(const bf16x8*)&ks[s * 4096 + t * 1024 + krd1];
                acc = __builtin_amdgcn_mfma_f32_16x16x32_bf16(kf0, qf[0], acc, 0, 0, 0);
                acc = __builtin_amdgcn_mfma_f32_16x16x32_bf16(kf1, qf[1], acc, 0, 0, 0);
                float p0 = fexp2(acc[0]), p1 = fexp2(acc[1]);
                float p2 = fexp2(acc[2]), p3 = fexp2(acc[3]);
                rs += (p0 + p1) + (p2 + p3);
                union { bf16x4 v; uint2 u; } x;
                x.u = make_uint2(pack2(p0, p1), pack2(p2, p3));
                pf[s][t] = x.v;
            }
            l_r += rs;
        }

        // ---- O^T += V^T P^T, both tiles: conflict-free b64 reads ----
#pragma unroll
        for (int s = 0; s < 2; ++s)
#pragma unroll
            for (int c = 0; c < 4; ++c)
#pragma unroll
                for (int t2 = 0; t2 < 4; ++t2) {
                    bf16x4 vf = *(const bf16x4*)&vt[s * 4096 + (c * 4 + t2) * 256 + vrd];
                    o_acc[t2] = mfma16(vf, pf[s][c], o_acc[t2]);
                }

        if (ip + 1 < NP) stage(cur ^ 1);    // vmcnt drain lands post-compute
        __syncthreads();                    // ONE barrier per 2 tiles
    }

    // ---- epilogue: reduce l across the 4 quads, normalize, store fp32 ----
    l_r += __shfl_xor(l_r, 16);
    l_r += __shfl_xor(l_r, 32);
    const float inv = 1.0f / l_r;
    float* op = outg + (size_t)(b * S_ + qrow) * ROWSZ + h * D_;
#pragma unroll
    for (int t2 = 0; t2 < 4; ++t2)
#pragma unroll
        for (int r = 0; r < 4; ++r)
            op[t2 * 16 + g * 4 + r] = o_acc[t2][r] * inv;
}

extern "C" void kernel_launch(void* const* d_in, const int* in_sizes, int n_in,
                              void* d_out, int out_size, void* d_ws, size_t ws_size,
                              hipStream_t stream) {
    dim3 grid(S_ / BQ, H_, B_);   // (16,16,2) = 512 blocks, 2/CU
    fattn_kernel<<<grid, dim3(512), 0, stream>>>(
        (const float*)d_in[0], (const float*)d_in[1], (const float*)d_in[2],
        (const float*)d_in[3], (float*)d_out);
}

// Round 16
// 142.047 us; speedup vs baseline: 1.0575x; 1.0575x over previous
//
#include <hip/hip_runtime.h>
#include <hip/hip_bf16.h>

// Round 15 = r9 VERBATIM (best measured: 72-76us kernel, 144.9us bench)
// + two zero-numerics-risk catalog grafts:
//  T1 XCD swizzle: lin -> (lin&7)*64 + lin>>3 (bijective, 512=8*64).
//     Default dispatch round-robins the 16 qt-blocks sharing one (b,h)'s
//     K/V slab across all 8 XCDs (8x L3 re-fetch). Swizzled: each XCD gets
//     4 heads x 16 qt contiguous -> K/V working set 4MB = one XCD L2 ->
//     K/V staging loads become L2 hits, shortening the per-barrier vmcnt
//     drain (the residual stall).
//  T5 setprio(1) around compute: 2 independent blocks/CU -> scheduler can
//     favor a compute-phase wave over the other block's staging waves
//     (measured +4-7% on attn in this regime).
// Structural post-mortem: conflicts (r9), occupancy (r10/r12), LDS pressure
// (r13), barrier count (r14) ALL exonerated by counters -- MFMA/VALU busy
// time invariant ~20.5/~33us across every variant; r9 is the 2-phase
// family's local optimum. If this round's delta <3%, declare ceiling.

typedef __attribute__((ext_vector_type(8))) short bf16x8;
typedef __attribute__((ext_vector_type(4))) short bf16x4;
typedef __attribute__((ext_vector_type(4))) float f32x4;

#define B_ 2
#define S_ 2048
#define H_ 16
#define D_ 64
#define BQ 128
#define BK 64
#define NT (S_ / BK)
#define ROWSZ (H_ * D_)        // 1024 floats between s rows

#define LOG2E  1.44269504088896340736f
#define SCALE2 (0.125f * LOG2E)

__device__ __forceinline__ unsigned pack2(float a, float b) {
    union { __hip_bfloat162 h; unsigned u; } x;
    x.h = __float22bfloat162_rn(make_float2(a, b));   // v_cvt_pk_bf16_f32
    return x.u;
}

__device__ __forceinline__ float fexp2(float x) {
#if __has_builtin(__builtin_amdgcn_exp2f)
    return __builtin_amdgcn_exp2f(x);
#else
    return __expf(x * 0.69314718055994531f);
#endif
}

__device__ __forceinline__ f32x4 mfma16(bf16x4 a, bf16x4 b, f32x4 c) {
#if __has_builtin(__builtin_amdgcn_mfma_f32_16x16x16bf16_1k)
    return __builtin_amdgcn_mfma_f32_16x16x16bf16_1k(a, b, c, 0, 0, 0);
#else
    bf16x8 a8 = {a[0], a[1], a[2], a[3], 0, 0, 0, 0};
    bf16x8 b8 = {b[0], b[1], b[2], b[3], 0, 0, 0, 0};
    return __builtin_amdgcn_mfma_f32_16x16x32_bf16(a8, b8, c, 0, 0, 0);
#endif
}

__global__ __launch_bounds__(512, 4)
void fattn_kernel(const float* __restrict__ qg,
                  const float* __restrict__ kg,
                  const float* __restrict__ vg,
                  const float* __restrict__ maskg,
                  float* __restrict__ outg)
{
    __shared__ __attribute__((aligned(16))) ushort Ks[2][4096];
    __shared__ __attribute__((aligned(16))) ushort Vt[2][4096];
    __shared__ __attribute__((aligned(16))) float  Em[S_];   // mask * log2e

    // ---- T1: XCD-aware remap (bijective over 512 blocks = 8 XCD x 64) ----
    const int lin = blockIdx.x + 16 * (blockIdx.y + 16 * blockIdx.z);
    const int swz = (lin & 7) * 64 + (lin >> 3);
    const int qt = swz & 15, h = (swz >> 4) & 15, b = swz >> 8;

    const int tid = threadIdx.x;
    const int w = tid >> 6, lane = tid & 63, g = lane >> 4, l15 = lane & 15;

    // ---- stage pre-scaled mask to LDS (once) ----
    {
        float4 mv = *(const float4*)(maskg + (size_t)b * S_ + tid * 4);
        *(float4*)&Em[tid * 4] = make_float4(mv.x * LOG2E, mv.y * LOG2E,
                                             mv.z * LOG2E, mv.w * LOG2E);
    }

    // ---- Q fragment (B-operand, x32), scale folded in ----
    const int qrow = qt * BQ + w * 16 + l15;
    const float* qp = qg + (size_t)(b * S_ + qrow) * ROWSZ + h * D_;
    bf16x8 qf[2];
#pragma unroll
    for (int half = 0; half < 2; ++half) {
        float4 f0 = *(const float4*)(qp + half * 32 + g * 8);
        float4 f1 = *(const float4*)(qp + half * 32 + g * 8 + 4);
        union { bf16x8 v; uint4 u; } x;
        x.u = make_uint4(pack2(f0.x * SCALE2, f0.y * SCALE2),
                         pack2(f0.z * SCALE2, f0.w * SCALE2),
                         pack2(f1.x * SCALE2, f1.y * SCALE2),
                         pack2(f1.z * SCALE2, f1.w * SCALE2));
        qf[half] = x.v;
    }

    // ---- staging maps (conflict-free layouts, verified r9) ----
    const int skey = tid >> 4;
    const int sd   = (tid & 15) * 4;
    const int kw0 = (skey >> 4) * 1024
                  + ((sd >> 3) + ((skey >> 3) & 1) * 8) * 64
                  + (((skey & 7) ^ (sd >> 3)) << 3) + (sd & 7);
    const int kw1 = kw0 + 2048;
    const int vwA = ((w >> 1) * 4 + (lane >> 4)) * 256
                  + ((2 * w) & 3) * 64 + (lane & 15) * 4;
    const int vwB = vwA + 64;

    const size_t kvbase = (size_t)b * S_ * ROWSZ + h * D_;

    float4 kpre0, kpre1;
    float  vpre[8];
    auto prefetch = [&](int kt) {
        const float* kb = kg + kvbase + (size_t)kt * BK * ROWSZ;
        kpre0 = *(const float4*)(kb + (size_t)skey * ROWSZ + sd);
        kpre1 = *(const float4*)(kb + (size_t)(skey + 32) * ROWSZ + sd);
        const float* vb = vg + kvbase + (size_t)kt * BK * ROWSZ + lane;
#pragma unroll
        for (int i = 0; i < 8; ++i) vpre[i] = vb[(size_t)(w * 8 + i) * ROWSZ];
    };
    auto stage = [&](int buf) {
        *(uint2*)&Ks[buf][kw0] =
            make_uint2(pack2(kpre0.x, kpre0.y), pack2(kpre0.z, kpre0.w));
        *(uint2*)&Ks[buf][kw1] =
            make_uint2(pack2(kpre1.x, kpre1.y), pack2(kpre1.z, kpre1.w));
        *(uint2*)&Vt[buf][vwA] =
            make_uint2(pack2(vpre[0], vpre[1]), pack2(vpre[2], vpre[3]));
        *(uint2*)&Vt[buf][vwB] =
            make_uint2(pack2(vpre[4], vpre[5]), pack2(vpre[6], vpre[7]));
    };

    float l_r = 0.0f;                   // per-lane (q=l15) partial denominator
    f32x4 o_acc[4];
#pragma unroll
    for (int t = 0; t < 4; ++t) o_acc[t] = (f32x4){0.f, 0.f, 0.f, 0.f};

    prefetch(0);
    stage(0);
    __syncthreads();                    // also covers Em staging

    // ---- read bases (thread-constant; reads at immediate offsets) ----
    const int krd0 = (g + (l15 >> 3) * 8) * 64 + (((l15 & 7) ^ g) << 3);
    const int krd1 = (g + 4 + (l15 >> 3) * 8) * 64 + (((l15 & 7) ^ (g + 4)) << 3);
    const int vrd = g * 64 + l15 * 4;

    for (int kt = 0; kt < NT; ++kt) {
        const int cur = kt & 1;
        if (kt + 1 < NT) prefetch(kt + 1);   // loads in flight across compute

        // ---- T5: favor this wave while it's in the compute phase ----
        __builtin_amdgcn_s_setprio(1);

        // ---- St = K Q^T + mask (C-init) : St[key][q=l15] ----
        const ushort* ks = Ks[cur];
        float sv[4][4];
#pragma unroll
        for (int t = 0; t < 4; ++t) {
            f32x4 acc = *(const f32x4*)&Em[kt * BK + t * 16 + g * 4];  // bcast
            bf16x8 kf0 = *(const bf16x8*)&ks[t * 1024 + krd0];
            bf16x8 kf1 = *(const bf16x8*)&ks[t * 1024 + krd1];
            acc = __builtin_amdgcn_mfma_f32_16x16x32_bf16(kf0, qf[0], acc, 0, 0, 0);
            acc = __builtin_amdgcn_mfma_f32_16x16x32_bf16(kf1, qf[1], acc, 0, 0, 0);
            sv[t][0] = acc[0]; sv[t][1] = acc[1]; sv[t][2] = acc[2]; sv[t][3] = acc[3];
        }

        // ---- fixed-base softmax: p = exp2(s); l += sum ----
        float rs = 0.f;
#pragma unroll
        for (int t = 0; t < 4; ++t)
#pragma unroll
            for (int r = 0; r < 4; ++r) {
                float p = fexp2(sv[t][r]);
                sv[t][r] = p;
                rs += p;
            }
        l_r += rs;

        // ---- P^T fragments direct from regs ----
        bf16x4 pf[4];
#pragma unroll
        for (int c = 0; c < 4; ++c) {
            union { bf16x4 v; uint2 u; } x;
            x.u = make_uint2(pack2(sv[c][0], sv[c][1]), pack2(sv[c][2], sv[c][3]));
            pf[c] = x.v;
        }

        // ---- O^T += V^T P^T : conflict-free b64 reads, 4 acc chains ----
        const ushort* vt = Vt[cur];
#pragma unroll
        for (int c = 0; c < 4; ++c)
#pragma unroll
            for (int t2 = 0; t2 < 4; ++t2) {
                bf16x4 vf = *(const bf16x4*)&vt[(c * 4 + t2) * 256 + vrd];
                o_acc[t2] = mfma16(vf, pf[c], o_acc[t2]);
            }

        __builtin_amdgcn_s_setprio(0);

        if (kt + 1 < NT) stage(cur ^ 1);    // vmcnt drain lands post-compute
        __syncthreads();                    // single barrier per tile
    }

    // ---- epilogue: reduce l across the 4 quads, normalize, store fp32 ----
    l_r += __shfl_xor(l_r, 16);
    l_r += __shfl_xor(l_r, 32);
    const float inv = 1.0f / l_r;
    float* op = outg + (size_t)(b * S_ + qrow) * ROWSZ + h * D_;
#pragma unroll
    for (int t2 = 0; t2 < 4; ++t2)
#pragma unroll
        for (int r = 0; r < 4; ++r)
            op[t2 * 16 + g * 4 + r] = o_acc[t2][r] * inv;
}

extern "C" void kernel_launch(void* const* d_in, const int* in_sizes, int n_in,
                              void* d_out, int out_size, void* d_ws, size_t ws_size,
                              hipStream_t stream) {
    dim3 grid(S_ / BQ, H_, B_);   // (16,16,2) = 512 blocks, 2/CU
    fattn_kernel<<<grid, dim3(512), 0, stream>>>(
        (const float*)d_in[0], (const float*)d_in[1], (const float*)d_in[2],
        (const float*)d_in[3], (float*)d_out);
}